// Round 3
// baseline (609.688 us; speedup 1.0000x reference)
//
#include <hip/hip_runtime.h>

#define INPUT 32
#define HIDDEN 64
#define BATCH 4096
#define SEQ 256

__device__ __forceinline__ float readlane_f(float v, int l) {
    return __uint_as_float(__builtin_amdgcn_readlane(__float_as_uint(v), l));
}

// Pin a value into a VGPR: asm results cannot be rematerialized, so the
// allocator must keep these live across the t-loop instead of re-loading
// from global each iteration (rounds 1-2: VGPR_Count=52..56 proved the
// 96 weight floats were being rematerialized in-loop -> 426us).
#define PIN4(f) asm volatile("" : "+v"(f.x), "+v"(f.y), "+v"(f.z), "+v"(f.w))
#define PIN1(s) asm volatile("" : "+v"(s))

// One wave (64 lanes) per batch chain. Lane j owns hidden unit j:
// W_hh row j (64 VGPRs) + W_ih row j (32 VGPRs) pinned register-resident,
// h[k] broadcast via v_readlane -> SGPR fmac operand, x via scalar loads.
__global__ __launch_bounds__(256, 4) void rnn_fused_kernel(
    const float* __restrict__ x,     // [B, T, 32]
    const float* __restrict__ W_ih,  // [64, 32]
    const float* __restrict__ W_hh,  // [64, 64]
    const float* __restrict__ b_ih,  // [64]
    const float* __restrict__ b_hh,  // [64]
    const float* __restrict__ W_fc,  // [1, 64]
    const float* __restrict__ b_fc,  // [1]
    float* __restrict__ out)         // [B, 1]
{
    const int lane = threadIdx.x & 63;
    int b = blockIdx.x * 4 + (threadIdx.x >> 6);
    b = __builtin_amdgcn_readfirstlane(b);  // uniform -> x loads scalarize

    // W_hh row `lane`: 16 float4 = 64 VGPRs, loaded once.
    const float4* __restrict__ wr = (const float4*)(W_hh + lane * HIDDEN);
    float4 W0 = wr[0],  W1 = wr[1],  W2 = wr[2],  W3 = wr[3];
    float4 W4 = wr[4],  W5 = wr[5],  W6 = wr[6],  W7 = wr[7];
    float4 W8 = wr[8],  W9 = wr[9],  W10 = wr[10], W11 = wr[11];
    float4 W12 = wr[12], W13 = wr[13], W14 = wr[14], W15 = wr[15];

    // W_ih row `lane`: 8 float4 = 32 VGPRs.
    const float4* __restrict__ vr = (const float4*)(W_ih + lane * INPUT);
    float4 V0 = vr[0], V1 = vr[1], V2 = vr[2], V3 = vr[3];
    float4 V4 = vr[4], V5 = vr[5], V6 = vr[6], V7 = vr[7];

    float bias = b_ih[lane] + b_hh[lane];

    // Force residency: these definitions are opaque to the optimizer.
    PIN4(W0);  PIN4(W1);  PIN4(W2);  PIN4(W3);
    PIN4(W4);  PIN4(W5);  PIN4(W6);  PIN4(W7);
    PIN4(W8);  PIN4(W9);  PIN4(W10); PIN4(W11);
    PIN4(W12); PIN4(W13); PIN4(W14); PIN4(W15);
    PIN4(V0);  PIN4(V1);  PIN4(V2);  PIN4(V3);
    PIN4(V4);  PIN4(V5);  PIN4(V6);  PIN4(V7);
    PIN1(bias);

    const float* __restrict__ xb = x + (size_t)b * SEQ * INPUT;

    float h = 0.0f;

#define IH(q) do { \
        a0 = fmaf(V##q.x, xt[4*q + 0], a0); \
        a1 = fmaf(V##q.y, xt[4*q + 1], a1); \
        a2 = fmaf(V##q.z, xt[4*q + 2], a2); \
        a3 = fmaf(V##q.w, xt[4*q + 3], a3); } while (0)

#define HH(q) do { \
        a0 = fmaf(W##q.x, readlane_f(h, 4*q + 0), a0); \
        a1 = fmaf(W##q.y, readlane_f(h, 4*q + 1), a1); \
        a2 = fmaf(W##q.z, readlane_f(h, 4*q + 2), a2); \
        a3 = fmaf(W##q.w, readlane_f(h, 4*q + 3), a3); } while (0)

#pragma unroll 1
    for (int t = 0; t < SEQ; ++t) {
        const float* __restrict__ xt = xb + t * INPUT;  // wave-uniform -> s_load

        float a0 = bias, a1 = 0.0f, a2 = 0.0f, a3 = 0.0f;

        // Input projection: x values wave-uniform (SMEM pipe), weights VGPR.
        IH(0); IH(1); IH(2); IH(3); IH(4); IH(5); IH(6); IH(7);

        // Recurrent matvec: h[k] broadcast via v_readlane (VALU pipe, no LDS).
        HH(0);  HH(1);  HH(2);  HH(3);  HH(4);  HH(5);  HH(6);  HH(7);
        HH(8);  HH(9);  HH(10); HH(11); HH(12); HH(13); HH(14); HH(15);

        float pre = (a0 + a1) + (a2 + a3);
        // tanh(p) = 1 - 2/(exp(2p)+1)
        float e = __expf(2.0f * pre);
        h = 1.0f - 2.0f * __builtin_amdgcn_rcpf(e + 1.0f);
    }
#undef IH
#undef HH

    // Head: out[b] = sum_j h[j]*W_fc[j] + b_fc (once per chain, cost ~0).
    float v = h * W_fc[lane];
#pragma unroll
    for (int off = 32; off > 0; off >>= 1) v += __shfl_xor(v, off, 64);
    if (lane == 0) out[b] = v + b_fc[0];
}

extern "C" void kernel_launch(void* const* d_in, const int* in_sizes, int n_in,
                              void* d_out, int out_size, void* d_ws, size_t ws_size,
                              hipStream_t stream) {
    const float* x    = (const float*)d_in[0];
    const float* W_ih = (const float*)d_in[1];
    const float* W_hh = (const float*)d_in[2];
    const float* b_ih = (const float*)d_in[3];
    const float* b_hh = (const float*)d_in[4];
    const float* W_fc = (const float*)d_in[5];
    const float* b_fc = (const float*)d_in[6];
    float* out = (float*)d_out;

    // 4096 batch chains, one wave each: 1024 blocks x 256 threads (4 waves/block).
    rnn_fused_kernel<<<dim3(BATCH / 4), dim3(256), 0, stream>>>(
        x, W_ih, W_hh, b_ih, b_hh, W_fc, b_fc, out);
}

// Round 4
// 515.081 us; speedup vs baseline: 1.1837x; 1.1837x over previous
//
#include <hip/hip_runtime.h>

#define INPUT 32
#define HIDDEN 64
#define BATCH 4096
#define SEQ 256

__device__ __forceinline__ float readlane_f(float v, int l) {
    return __uint_as_float(__builtin_amdgcn_readlane(__float_as_uint(v), l));
}

// Pin a value into a VGPR (asm results can't be rematerialized).
#define PIN4(f) asm volatile("" : "+v"(f.x), "+v"(f.y), "+v"(f.z), "+v"(f.w))
#define PIN1(s) asm volatile("" : "+v"(s))

// One wave (64 lanes) per batch chain. Lane j owns hidden unit j:
// W_hh row j (64 VGPRs) + W_ih row j (32 VGPRs) register-resident,
// h[k] broadcast via v_readlane -> SGPR fmac operand, x via scalar loads.
//
// ROUND 3 FINDING: under __launch_bounds__(256,4) (128-VGPR cap) the
// allocator refused to keep the 96 weight floats live (VGPR_Count=52 even
// with asm pins -> it spilled the pins to scratch, dur 479us). Pre-RA
// remat/sink heuristics go aggressive when estimated pressure (~122) is
// near the cap (128). Fix: (256,2) -> 256-VGPR budget, 2 waves/SIMD.
// Trade 2x occupancy for ~2.5x fewer issued insts + no scratch.
__global__ __launch_bounds__(256, 2) void rnn_fused_kernel(
    const float* __restrict__ x,     // [B, T, 32]
    const float* __restrict__ W_ih,  // [64, 32]
    const float* __restrict__ W_hh,  // [64, 64]
    const float* __restrict__ b_ih,  // [64]
    const float* __restrict__ b_hh,  // [64]
    const float* __restrict__ W_fc,  // [1, 64]
    const float* __restrict__ b_fc,  // [1]
    float* __restrict__ out)         // [B, 1]
{
    const int lane = threadIdx.x & 63;
    int b = blockIdx.x * 4 + (threadIdx.x >> 6);
    b = __builtin_amdgcn_readfirstlane(b);  // uniform -> x loads scalarize

    // W_hh row `lane`: 16 float4 = 64 VGPRs, loaded once.
    const float4* __restrict__ wr = (const float4*)(W_hh + lane * HIDDEN);
    float4 W0 = wr[0],  W1 = wr[1],  W2 = wr[2],  W3 = wr[3];
    float4 W4 = wr[4],  W5 = wr[5],  W6 = wr[6],  W7 = wr[7];
    float4 W8 = wr[8],  W9 = wr[9],  W10 = wr[10], W11 = wr[11];
    float4 W12 = wr[12], W13 = wr[13], W14 = wr[14], W15 = wr[15];

    // W_ih row `lane`: 8 float4 = 32 VGPRs.
    const float4* __restrict__ vr = (const float4*)(W_ih + lane * INPUT);
    float4 V0 = vr[0], V1 = vr[1], V2 = vr[2], V3 = vr[3];
    float4 V4 = vr[4], V5 = vr[5], V6 = vr[6], V7 = vr[7];

    float bias = b_ih[lane] + b_hh[lane];

    // Force residency (harmless now that the budget fits them comfortably).
    PIN4(W0);  PIN4(W1);  PIN4(W2);  PIN4(W3);
    PIN4(W4);  PIN4(W5);  PIN4(W6);  PIN4(W7);
    PIN4(W8);  PIN4(W9);  PIN4(W10); PIN4(W11);
    PIN4(W12); PIN4(W13); PIN4(W14); PIN4(W15);
    PIN4(V0);  PIN4(V1);  PIN4(V2);  PIN4(V3);
    PIN4(V4);  PIN4(V5);  PIN4(V6);  PIN4(V7);
    PIN1(bias);

    const float* __restrict__ xb = x + (size_t)b * SEQ * INPUT;

    float h = 0.0f;

#define IH(q) do { \
        a0 = fmaf(V##q.x, xt[4*q + 0], a0); \
        a1 = fmaf(V##q.y, xt[4*q + 1], a1); \
        a2 = fmaf(V##q.z, xt[4*q + 2], a2); \
        a3 = fmaf(V##q.w, xt[4*q + 3], a3); } while (0)

#define HH(q) do { \
        a0 = fmaf(W##q.x, readlane_f(h, 4*q + 0), a0); \
        a1 = fmaf(W##q.y, readlane_f(h, 4*q + 1), a1); \
        a2 = fmaf(W##q.z, readlane_f(h, 4*q + 2), a2); \
        a3 = fmaf(W##q.w, readlane_f(h, 4*q + 3), a3); } while (0)

#pragma unroll 1
    for (int t = 0; t < SEQ; ++t) {
        const float* __restrict__ xt = xb + t * INPUT;  // wave-uniform -> s_load

        float a0 = bias, a1 = 0.0f, a2 = 0.0f, a3 = 0.0f;

        // Input projection: x values wave-uniform (SMEM pipe), weights VGPR.
        IH(0); IH(1); IH(2); IH(3); IH(4); IH(5); IH(6); IH(7);

        // Recurrent matvec: h[k] broadcast via v_readlane (VALU pipe, no LDS).
        HH(0);  HH(1);  HH(2);  HH(3);  HH(4);  HH(5);  HH(6);  HH(7);
        HH(8);  HH(9);  HH(10); HH(11); HH(12); HH(13); HH(14); HH(15);

        float pre = (a0 + a1) + (a2 + a3);
        // tanh(p) = 1 - 2/(exp(2p)+1)
        float e = __expf(2.0f * pre);
        h = 1.0f - 2.0f * __builtin_amdgcn_rcpf(e + 1.0f);
    }
#undef IH
#undef HH

    // Head: out[b] = sum_j h[j]*W_fc[j] + b_fc (once per chain, cost ~0).
    float v = h * W_fc[lane];
#pragma unroll
    for (int off = 32; off > 0; off >>= 1) v += __shfl_xor(v, off, 64);
    if (lane == 0) out[b] = v + b_fc[0];
}

extern "C" void kernel_launch(void* const* d_in, const int* in_sizes, int n_in,
                              void* d_out, int out_size, void* d_ws, size_t ws_size,
                              hipStream_t stream) {
    const float* x    = (const float*)d_in[0];
    const float* W_ih = (const float*)d_in[1];
    const float* W_hh = (const float*)d_in[2];
    const float* b_ih = (const float*)d_in[3];
    const float* b_hh = (const float*)d_in[4];
    const float* W_fc = (const float*)d_in[5];
    const float* b_fc = (const float*)d_in[6];
    float* out = (float*)d_out;

    // 4096 batch chains, one wave each: 1024 blocks x 256 threads (4 waves/block).
    rnn_fused_kernel<<<dim3(BATCH / 4), dim3(256), 0, stream>>>(
        x, W_ih, W_hh, b_ih, b_hh, W_fc, b_fc, out);
}

// Round 5
// 478.199 us; speedup vs baseline: 1.2750x; 1.0771x over previous
//
#include <hip/hip_runtime.h>

#define INPUT 32
#define HIDDEN 64
#define BATCH 4096
#define SEQ 256

typedef __attribute__((ext_vector_type(8))) short bf16x8;   // 8 bf16 (4 VGPRs)
typedef __attribute__((ext_vector_type(4))) float floatx4;  // 4 fp32

#define MFMA(a, b, c) __builtin_amdgcn_mfma_f32_16x16x32_bf16((a), (b), (c), 0, 0, 0)

// f32 -> bf16 bits, round-to-nearest-even.
__device__ __forceinline__ unsigned short f2bf(float f) {
    unsigned u = __float_as_uint(f);
    u += 0x7fffu + ((u >> 16) & 1u);
    return (unsigned short)(u >> 16);
}
__device__ __forceinline__ float bf2f(unsigned short b) {
    return __uint_as_float(((unsigned)b) << 16);
}

// Split 8 fp32 into hi/lo bf16 fragments (hi+lo carries ~16 mantissa bits).
__device__ __forceinline__ void split8(const float f[8], bf16x8& hi, bf16x8& lo) {
#pragma unroll
    for (int j = 0; j < 8; ++j) {
        unsigned short h = f2bf(f[j]);
        hi[j] = (short)h;
        lo[j] = (short)f2bf(f[j] - bf2f(h));
    }
}

// One wave = 16 batch chains. Per timestep:
//   acc[16,64] = bias + X_t(16x32)@W_ih^T + H(16x64)@W_hh^T   (3-term bf16 split)
//   H = tanh(acc), round-tripped through LDS (C-layout -> A-layout).
// MFMA layouts (verified, m89/m120): C/D: col=lane&15, row=(lane>>4)*4+reg.
//                                    A:   m=lane&15,  k=(lane>>4)*8+j.
//                                    B:   n=lane&15,  k=(lane>>4)*8+j.
// Rounds 1-4 lesson: VALU structure floor is 82us (157 TF); MFMA floor ~10us.
// launch_bounds(64,1): 512-VGPR budget, pressure ~180 -> no remat pressure.
__global__ __launch_bounds__(64, 1) void rnn_mfma_kernel(
    const float* __restrict__ x,     // [B, T, 32]
    const float* __restrict__ W_ih,  // [64, 32]
    const float* __restrict__ W_hh,  // [64, 64]
    const float* __restrict__ b_ih,  // [64]
    const float* __restrict__ b_hh,  // [64]
    const float* __restrict__ W_fc,  // [1, 64]
    const float* __restrict__ b_fc,  // [1]
    float* __restrict__ out)         // [B, 1]
{
    const int lane = threadIdx.x;        // block = exactly one wave
    const int ln = lane & 15;
    const int qd = lane >> 4;
    const int b0 = blockIdx.x * 16;      // this wave's batch tile

    __shared__ float Hs[16 * 68];        // H row-major, stride 68 (pad: bank spread)

    // h_{-1} = 0
    for (int i = lane; i < 16 * 68; i += 64) Hs[i] = 0.0f;

    // ---- Build weight B-fragments once (hi/lo split) ----
    // hh: B[k][n] = W_hh[n][k], n = 16*nt+ln, k = 32*kt + 8*qd + j
    // ih: B[k][n] = W_ih[n][k], n = 16*nt+ln, k = 8*qd + j
    bf16x8 WhhH[4][2], WhhL[4][2], WihH[4], WihL[4];
    float bb[4], wfc[4];
#pragma unroll
    for (int nt = 0; nt < 4; ++nt) {
        const int n = nt * 16 + ln;
        const float* rh = W_hh + n * HIDDEN + qd * 8;
#pragma unroll
        for (int kt = 0; kt < 2; ++kt) {
            float f[8];
            *(float4*)&f[0] = *(const float4*)(rh + kt * 32);
            *(float4*)&f[4] = *(const float4*)(rh + kt * 32 + 4);
            split8(f, WhhH[nt][kt], WhhL[nt][kt]);
        }
        float g[8];
        const float* ri = W_ih + n * INPUT + qd * 8;
        *(float4*)&g[0] = *(const float4*)(ri);
        *(float4*)&g[4] = *(const float4*)(ri + 4);
        split8(g, WihH[nt], WihL[nt]);
        bb[nt] = b_ih[n] + b_hh[n];
        wfc[nt] = W_fc[n];
    }

    const float* xp = x + (size_t)(b0 + ln) * (SEQ * INPUT) + qd * 8;

#pragma unroll 1
    for (int t = 0; t < SEQ; ++t) {
        // x A-frag: A[m=ln][k=8qd+j] = x[b0+ln][t][8qd+j]  (32B/lane, L1-friendly)
        float xf[8];
        const float* xt = xp + t * INPUT;
        *(float4*)&xf[0] = *(const float4*)(xt);
        *(float4*)&xf[4] = *(const float4*)(xt + 4);

        // h A-frags: A[m=ln][k=32kt+8qd+j] = Hs[ln*68 + 32kt + 8qd + j]
        float hf0[8], hf1[8];
        const float* hr = Hs + ln * 68 + qd * 8;
        *(float4*)&hf0[0] = *(const float4*)(hr);
        *(float4*)&hf0[4] = *(const float4*)(hr + 4);
        *(float4*)&hf1[0] = *(const float4*)(hr + 32);
        *(float4*)&hf1[4] = *(const float4*)(hr + 36);

        bf16x8 xH, xL, h0H, h0L, h1H, h1L;
        split8(xf, xH, xL);
        split8(hf0, h0H, h0L);
        split8(hf1, h1H, h1L);

        floatx4 acc[4];
#pragma unroll
        for (int nt = 0; nt < 4; ++nt) {
            floatx4 a = {bb[nt], bb[nt], bb[nt], bb[nt]};  // bias: col-constant per lane
            a = MFMA(xH, WihH[nt], a);
            a = MFMA(xH, WihL[nt], a);
            a = MFMA(xL, WihH[nt], a);
            a = MFMA(h0H, WhhH[nt][0], a);
            a = MFMA(h0H, WhhL[nt][0], a);
            a = MFMA(h0L, WhhH[nt][0], a);
            a = MFMA(h1H, WhhH[nt][1], a);
            a = MFMA(h1H, WhhL[nt][1], a);
            a = MFMA(h1L, WhhH[nt][1], a);
            acc[nt] = a;
        }

        // tanh + write back in C layout: elem (nt,r) -> H[4qd+r][16nt+ln]
#pragma unroll
        for (int nt = 0; nt < 4; ++nt) {
#pragma unroll
            for (int r = 0; r < 4; ++r) {
                float p = acc[nt][r];
                float e = __expf(2.0f * p);
                float h = 1.0f - 2.0f * __builtin_amdgcn_rcpf(e + 1.0f);
                Hs[(qd * 4 + r) * 68 + nt * 16 + ln] = h;
            }
        }
        // Single wave: same-wave LDS ops execute in order; no barrier needed.
    }

    // ---- Head: out[b0+m] = sum_n H[m][n] * W_fc[n] + b_fc ----
    float s[4] = {0.f, 0.f, 0.f, 0.f};  // partials for rows m = 4qd + r
#pragma unroll
    for (int nt = 0; nt < 4; ++nt) {
#pragma unroll
        for (int r = 0; r < 4; ++r) {
            s[r] = fmaf(wfc[nt], Hs[(qd * 4 + r) * 68 + nt * 16 + ln], s[r]);
        }
    }
    // reduce over the 16 lanes sharing qd (xor in low 4 bits stays in-group)
#pragma unroll
    for (int off = 1; off < 16; off <<= 1) {
#pragma unroll
        for (int r = 0; r < 4; ++r) s[r] += __shfl_xor(s[r], off, 64);
    }
    if (ln == 0) {
        const float bf = b_fc[0];
#pragma unroll
        for (int r = 0; r < 4; ++r) out[b0 + qd * 4 + r] = s[r] + bf;
    }
}

extern "C" void kernel_launch(void* const* d_in, const int* in_sizes, int n_in,
                              void* d_out, int out_size, void* d_ws, size_t ws_size,
                              hipStream_t stream) {
    const float* x    = (const float*)d_in[0];
    const float* W_ih = (const float*)d_in[1];
    const float* W_hh = (const float*)d_in[2];
    const float* b_ih = (const float*)d_in[3];
    const float* b_hh = (const float*)d_in[4];
    const float* W_fc = (const float*)d_in[5];
    const float* b_fc = (const float*)d_in[6];
    float* out = (float*)d_out;

    // 256 tiles of 16 chains; 1 wave per block -> spread across all 256 CUs.
    rnn_mfma_kernel<<<dim3(BATCH / 16), dim3(64), 0, stream>>>(
        x, W_ih, W_hh, b_ih, b_hh, W_fc, b_fc, out);
}

// Round 6
// 404.743 us; speedup vs baseline: 1.5064x; 1.1815x over previous
//
#include <hip/hip_runtime.h>

#define INPUT 32
#define HIDDEN 64
#define BATCH 4096
#define SEQ 256

typedef __attribute__((ext_vector_type(8))) short bf16x8;   // 8 bf16 (4 VGPRs)
typedef __attribute__((ext_vector_type(4))) float floatx4;  // 4 fp32

#define MFMA(a, b, c) __builtin_amdgcn_mfma_f32_16x16x32_bf16((a), (b), (c), 0, 0, 0)

// f32 -> bf16 bits, round-to-nearest-even.
__device__ __forceinline__ unsigned short f2bf(float f) {
    unsigned u = __float_as_uint(f);
    u += 0x7fffu + ((u >> 16) & 1u);
    return (unsigned short)(u >> 16);
}
__device__ __forceinline__ float bf2f(unsigned short b) {
    return __uint_as_float(((unsigned)b) << 16);
}
__device__ __forceinline__ void split8(const float f[8], bf16x8& hi, bf16x8& lo) {
#pragma unroll
    for (int j = 0; j < 8; ++j) {
        unsigned short h = f2bf(f[j]);
        hi[j] = (short)h;
        lo[j] = (short)f2bf(f[j] - bf2f(h));
    }
}

// Round-5 lesson: 1 wave/CU = pure latency bound (MfmaUtil 4.5%, VALU 10.7%,
// 3140 cyc/step). This version: block = 4 waves (one per SIMD), wave nt owns
// output columns [16nt,16nt+16) -> per-wave chain is 6 hh-MFMAs, not 36.
// H lives in LDS as bf16 hi/lo planes ALREADY in A-frag layout (writer-side
// split): readers do 4 ds_read_b128 and zero split VALU. XOR swizzle
// (qd ^ (m>>2)) makes frag reads cover contiguous 1KB -> conflict-free.
// Double buffer -> one barrier per step. x prefetched one step ahead.
//
// LDS u16 index: buf*2048 + pl*1024 + kt*512 + m*32 + (qd_a ^ (m>>2))*8 + j
//   where element (m, k): kt=k>>5, qd_a=(k>>3)&3, j=k&7.
// MFMA layouts (verified r5): C/D col=lane&15,row=(lane>>4)*4+reg;
//                             A m=lane&15,k=(lane>>4)*8+j; B n=lane&15, same k.
__global__ __launch_bounds__(256, 1) void rnn_mfma4_kernel(
    const float* __restrict__ x,     // [B, T, 32]
    const float* __restrict__ W_ih,  // [64, 32]
    const float* __restrict__ W_hh,  // [64, 64]
    const float* __restrict__ b_ih,  // [64]
    const float* __restrict__ b_hh,  // [64]
    const float* __restrict__ W_fc,  // [1, 64]
    const float* __restrict__ b_fc,  // [1]
    float* __restrict__ out)         // [B, 1]
{
    const int tid  = threadIdx.x;
    const int nt   = tid >> 6;       // wave id = n-tile (0..3)
    const int lane = tid & 63;
    const int ln   = lane & 15;
    const int qd   = lane >> 4;
    const int b0   = blockIdx.x * 16;

    __shared__ __align__(16) unsigned short Hbf[4096];  // 8 KB: 2 buf x 2 pl x 2 kt x 16m x 4qd x 8j

    // Zero buffer 0 (h_{-1} = 0): first 2048 u16 = 1024 u32.
    {
        unsigned* z = (unsigned*)Hbf;
        for (int i = tid; i < 1024; i += 256) z[i] = 0u;
    }

    const int n = nt * 16 + ln;      // this wave's output column for lane ln

    // ---- B-fragments (hi/lo split), built once ----
    bf16x8 WhhH[2], WhhL[2], WihH, WihL, WfcH[2], WfcL[2];
    {
        float f[8];
        const float* rh = W_hh + n * HIDDEN + qd * 8;
#pragma unroll
        for (int kt = 0; kt < 2; ++kt) {
            *(float4*)&f[0] = *(const float4*)(rh + kt * 32);
            *(float4*)&f[4] = *(const float4*)(rh + kt * 32 + 4);
            split8(f, WhhH[kt], WhhL[kt]);
        }
        const float* ri = W_ih + n * INPUT + qd * 8;
        *(float4*)&f[0] = *(const float4*)ri;
        *(float4*)&f[4] = *(const float4*)(ri + 4);
        split8(f, WihH, WihL);
        // W_fc as a B-frag with only column n'=0 populated (head GEMV via MFMA).
#pragma unroll
        for (int kt = 0; kt < 2; ++kt) {
#pragma unroll
            for (int j = 0; j < 8; ++j) f[j] = (ln == 0) ? W_fc[kt * 32 + qd * 8 + j] : 0.0f;
            split8(f, WfcH[kt], WfcL[kt]);
        }
    }
    const float bb = b_ih[n] + b_hh[n];

    const float* xp = x + (size_t)(b0 + ln) * (SEQ * INPUT) + qd * 8;

    // Reader: A-frag for (m=ln, k=32kt+8qd+j); swizzle slot = qd ^ ((ln>>2)&3).
    const int rd_off = ln * 32 + (qd ^ ((ln >> 2) & 3)) * 8;
    // Writer: element (m=4qd+r, k=n): kt=n>>5, slot=((n>>3)&3)^qd (m>>2 == qd), j=n&7.
    const int wr_off = ((n >> 5) * 512) + ((((n >> 3) & 3) ^ qd) * 8) + (ln & 7);

    __syncthreads();   // zero-init visible

    float4 xa = *(const float4*)xp;
    float4 xb = *(const float4*)(xp + 4);

    int buf = 0;
#pragma unroll 1
    for (int t = 0; t < SEQ; ++t) {
        // Prefetch x for t+1 (clamped re-load on last iter; harmless).
        const int tn = (t + 1 < SEQ) ? t + 1 : t;
        float4 xa2 = *(const float4*)(xp + tn * INPUT);
        float4 xb2 = *(const float4*)(xp + tn * INPUT + 4);

        // Split current x (off the h critical path).
        float xf[8];
        *(float4*)&xf[0] = xa; *(float4*)&xf[4] = xb;
        bf16x8 xH, xL;
        split8(xf, xH, xL);

        // h A-frags: 4 conflict-free ds_read_b128, no VALU split needed.
        const unsigned short* Hr = Hbf + buf * 2048 + rd_off;
        bf16x8 h0H = *(const bf16x8*)(Hr);          // pl0 kt0
        bf16x8 h1H = *(const bf16x8*)(Hr + 512);    // pl0 kt1
        bf16x8 h0L = *(const bf16x8*)(Hr + 1024);   // pl1 kt0
        bf16x8 h1L = *(const bf16x8*)(Hr + 1536);   // pl1 kt1

        // Two accumulators: dep chains 6 and 3 instead of 9.
        floatx4 a = {bb, bb, bb, bb};
        a = MFMA(xH, WihH, a);
        a = MFMA(xH, WihL, a);
        a = MFMA(xL, WihH, a);
        a = MFMA(h0H, WhhH[0], a);
        a = MFMA(h0H, WhhL[0], a);
        a = MFMA(h0L, WhhH[0], a);
        floatx4 a2 = {0.f, 0.f, 0.f, 0.f};
        a2 = MFMA(h1H, WhhH[1], a2);
        a2 = MFMA(h1H, WhhL[1], a2);
        a2 = MFMA(h1L, WhhH[1], a2);

        // tanh + writer-side split into the other buffer.
        unsigned short* Hw = Hbf + (buf ^ 1) * 2048 + wr_off;
#pragma unroll
        for (int r = 0; r < 4; ++r) {
            float p = a[r] + a2[r];
            float e = __expf(2.0f * p);
            float h = 1.0f - 2.0f * __builtin_amdgcn_rcpf(e + 1.0f);
            unsigned short hi = f2bf(h);
            unsigned short lo = f2bf(h - bf2f(hi));
            Hw[(qd * 4 + r) * 32]        = hi;   // hi plane
            Hw[(qd * 4 + r) * 32 + 1024] = lo;   // lo plane
        }
        __syncthreads();
        buf ^= 1;
        xa = xa2; xb = xb2;
    }
    // buf == 0 after an even number of flips; final H is in buffer 0.

    // ---- Head: out[b0+m] = sum_k H[m][k]*W_fc[k] + b_fc  (wave 0 only) ----
    if (nt == 0) {
        const unsigned short* Hr = Hbf + rd_off;
        bf16x8 h0H = *(const bf16x8*)(Hr);
        bf16x8 h1H = *(const bf16x8*)(Hr + 512);
        bf16x8 h0L = *(const bf16x8*)(Hr + 1024);
        bf16x8 h1L = *(const bf16x8*)(Hr + 1536);
        floatx4 a = {0.f, 0.f, 0.f, 0.f};
        a = MFMA(h0H, WfcH[0], a);
        a = MFMA(h0H, WfcL[0], a);
        a = MFMA(h0L, WfcH[0], a);
        a = MFMA(h1H, WfcH[1], a);
        a = MFMA(h1H, WfcL[1], a);
        a = MFMA(h1L, WfcH[1], a);
        if (ln == 0) {   // C column 0 holds the GEMV result; rows m=4qd+r
            const float bf = b_fc[0];
#pragma unroll
            for (int r = 0; r < 4; ++r) out[b0 + qd * 4 + r] = a[r] + bf;
        }
    }
}

extern "C" void kernel_launch(void* const* d_in, const int* in_sizes, int n_in,
                              void* d_out, int out_size, void* d_ws, size_t ws_size,
                              hipStream_t stream) {
    const float* x    = (const float*)d_in[0];
    const float* W_ih = (const float*)d_in[1];
    const float* W_hh = (const float*)d_in[2];
    const float* b_ih = (const float*)d_in[3];
    const float* b_hh = (const float*)d_in[4];
    const float* W_fc = (const float*)d_in[5];
    const float* b_fc = (const float*)d_in[6];
    float* out = (float*)d_out;

    // 256 tiles of 16 chains; 4 waves per block (one per SIMD), 1 block per CU.
    rnn_mfma4_kernel<<<dim3(BATCH / 16), dim3(256), 0, stream>>>(
        x, W_ih, W_hh, b_ih, b_hh, W_fc, b_fc, out);
}

// Round 7
// 375.728 us; speedup vs baseline: 1.6227x; 1.0772x over previous
//
#include <hip/hip_runtime.h>

#define INPUT 32
#define HIDDEN 64
#define BATCH 4096
#define SEQ 256

typedef __attribute__((ext_vector_type(8))) short bf16x8;   // 8 bf16 (4 VGPRs)
typedef __attribute__((ext_vector_type(4))) float floatx4;  // 4 fp32

#define MFMA(a, b, c) __builtin_amdgcn_mfma_f32_16x16x32_bf16((a), (b), (c), 0, 0, 0)

// RNE f32->bf16 (setup-only, accuracy-first for static weights).
__device__ __forceinline__ unsigned short f2bf(float f) {
    unsigned u = __float_as_uint(f);
    u += 0x7fffu + ((u >> 16) & 1u);
    return (unsigned short)(u >> 16);
}
__device__ __forceinline__ float bf2f(unsigned short b) {
    return __uint_as_float(((unsigned)b) << 16);
}
__device__ __forceinline__ void split8(const float f[8], bf16x8& hi, bf16x8& lo) {
#pragma unroll
    for (int j = 0; j < 8; ++j) {
        unsigned short h = f2bf(f[j]);
        hi[j] = (short)h;
        lo[j] = (short)f2bf(f[j] - bf2f(h));
    }
}

// Fast truncation split of a pair -> packed hi-word / lo-word (6 VALU).
// hi(f) = top16 bits of f (truncated bf16); lo = f - hi (then truncated).
// v_perm sel 0x07060302: D = (src_hi_operand.hi16 << 16) | src_lo_operand.hi16.
__device__ __forceinline__ void packpair(float f0, float f1, unsigned& hw, unsigned& lw) {
    unsigned b0 = __float_as_uint(f0), b1 = __float_as_uint(f1);
    float h0 = __uint_as_float(b0 & 0xffff0000u);
    float h1 = __uint_as_float(b1 & 0xffff0000u);
    float l0 = f0 - h0, l1 = f1 - h1;
    hw = __builtin_amdgcn_perm(b1, b0, 0x07060302u);
    lw = __builtin_amdgcn_perm(__float_as_uint(l1), __float_as_uint(l0), 0x07060302u);
}

union FragU { bf16x8 v; unsigned u[4]; };

// Round-6 diagnosis: the N-split structure was VALU-bound (2160 busy-cyc/step/CU)
// from duplicated x-splits + scalar f2bf, plus an 8-way-conflicted LDS layout.
// This version keeps the state TRANSPOSED: G = H^T held in MFMA C-layout and
// consumed as the B operand next step; W_ih/W_hh are static A operands
// (pre-split hi/lo, register-resident). Per wave/step VALU ~76 insts.
//
// Layouts (verified r5/r6): C/D: row=4*qd+reg (here: hidden u), col=ln (batch).
//   A: m=ln, k=8*qd+j (W rows).  B: n=ln (batch), k=8*qd+j (+32*kt).
// G in LDS (u16 idx): buf*2048 + pl*1024 + kt*512 + ln*32 + slot*8 + j,
//   slot = (qd_reader + (ln>>1)) & 3  -> both b128 reads and paired-b32
//   writes are <=2-way per phase (2-way measured free, m136).
__global__ __launch_bounds__(256, 1) void rnn_tg_kernel(
    const float* __restrict__ x,     // [B, T, 32]
    const float* __restrict__ W_ih,  // [64, 32]
    const float* __restrict__ W_hh,  // [64, 64]
    const float* __restrict__ b_ih,  // [64]
    const float* __restrict__ b_hh,  // [64]
    const float* __restrict__ W_fc,  // [1, 64]
    const float* __restrict__ b_fc,  // [1]
    float* __restrict__ out)         // [B, 1]
{
    const int tid  = threadIdx.x;
    const int nt   = tid >> 6;        // wave id: owns hidden rows [16nt, 16nt+16)
    const int lane = tid & 63;
    const int ln   = lane & 15;
    const int qd   = lane >> 4;
    const int b0   = blockIdx.x * 16;

    __shared__ __align__(16) unsigned short Hs[4096];  // 8 KB: 2 buffers of G hi/lo
    __shared__ float Ps[64];

    { // zero buffer 0 (h_{-1} = 0)
        unsigned* z = (unsigned*)Hs;
        for (int i = tid; i < 1024; i += 256) z[i] = 0u;
    }

    // ---- Static A-operand weights (row m = 16nt+ln), RNE hi/lo split ----
    const int mrow = nt * 16 + ln;
    bf16x8 WihH, WihL, WhhH[2], WhhL[2];
    {
        float f[8];
        const float* ri = W_ih + mrow * INPUT + qd * 8;
        *(float4*)&f[0] = *(const float4*)ri;
        *(float4*)&f[4] = *(const float4*)(ri + 4);
        split8(f, WihH, WihL);
        const float* rh = W_hh + mrow * HIDDEN + qd * 8;
#pragma unroll
        for (int kt = 0; kt < 2; ++kt) {
            *(float4*)&f[0] = *(const float4*)(rh + kt * 32);
            *(float4*)&f[4] = *(const float4*)(rh + kt * 32 + 4);
            split8(f, WhhH[kt], WhhL[kt]);
        }
    }
    // Bias / head weights for this lane's 4 output rows u = 16nt + 4qd + r.
    const int u0 = nt * 16 + qd * 4;
    floatx4 bbv, wfcv;
    {
        float4 bi = *(const float4*)(b_ih + u0);
        float4 bh = *(const float4*)(b_hh + u0);
        bbv[0] = bi.x + bh.x; bbv[1] = bi.y + bh.y;
        bbv[2] = bi.z + bh.z; bbv[3] = bi.w + bh.w;
        float4 wf = *(const float4*)(W_fc + u0);
        wfcv[0] = wf.x; wfcv[1] = wf.y; wfcv[2] = wf.z; wfcv[3] = wf.w;
    }

    // Reader offset (this lane's B-frag): + pl*1024 + kt*512 (+ buf*2048)
    const int rbase = ln * 32 + ((qd + (ln >> 1)) & 3) * 8;
    // Writer offsets for r-pairs p=0,1 (elements u = u0+2p, u0+2p+1):
    int woff[2];
#pragma unroll
    for (int p = 0; p < 2; ++p) {
        const int up = u0 + 2 * p;
        woff[p] = (up >> 5) * 512 + ln * 32 + ((((up >> 3) & 3) + (ln >> 1)) & 3) * 8 + (up & 7);
    }

    const float* xp = x + (size_t)(b0 + ln) * (SEQ * INPUT) + qd * 8;

    // 2-deep x prefetch (covers ~900-cyc HBM miss across ~2 steps).
    float4 xA0 = *(const float4*)(xp);
    float4 xB0 = *(const float4*)(xp + 4);
    float4 xA1 = *(const float4*)(xp + INPUT);
    float4 xB1 = *(const float4*)(xp + INPUT + 4);

    __syncthreads();  // zero-init visible

    float hv[4] = {0.f, 0.f, 0.f, 0.f};

#pragma unroll 1
    for (int t = 0; t < SEQ; ++t) {
        const int tn = (t + 2 < SEQ) ? t + 2 : SEQ - 1;
        float4 xA2 = *(const float4*)(xp + tn * INPUT);
        float4 xB2 = *(const float4*)(xp + tn * INPUT + 4);

        // x B-frag (hi/lo), 24 VALU.
        FragU xH, xL;
        packpair(xA0.x, xA0.y, xH.u[0], xL.u[0]);
        packpair(xA0.z, xA0.w, xH.u[1], xL.u[1]);
        packpair(xB0.x, xB0.y, xH.u[2], xL.u[2]);
        packpair(xB0.z, xB0.w, xH.u[3], xL.u[3]);

        // G B-frags: 4 x ds_read_b128, ~2-way max.
        const unsigned short* Hr = Hs + ((t & 1) << 11) + rbase;
        bf16x8 gH0 = *(const bf16x8*)(Hr);          // pl0 kt0
        bf16x8 gH1 = *(const bf16x8*)(Hr + 512);    // pl0 kt1
        bf16x8 gL0 = *(const bf16x8*)(Hr + 1024);   // pl1 kt0
        bf16x8 gL1 = *(const bf16x8*)(Hr + 1536);   // pl1 kt1

        // Two accumulators: 6-deep + 3-deep chains.
        floatx4 a = bbv;
        a = MFMA(WihH, xH.v, a);
        a = MFMA(WihH, xL.v, a);
        a = MFMA(WihL, xH.v, a);
        a = MFMA(WhhH[0], gH0, a);
        a = MFMA(WhhH[0], gL0, a);
        a = MFMA(WhhL[0], gH0, a);
        floatx4 a2 = {0.f, 0.f, 0.f, 0.f};
        a2 = MFMA(WhhH[1], gH1, a2);
        a2 = MFMA(WhhH[1], gL1, a2);
        a2 = MFMA(WhhL[1], gH1, a2);

        // tanh (4 elems) -> new G rows u0..u0+3 for batch col ln.
#pragma unroll
        for (int r = 0; r < 4; ++r) {
            float p = a[r] + a2[r];
            float e = __expf(2.0f * p);
            hv[r] = 1.0f - 2.0f * __builtin_amdgcn_rcpf(e + 1.0f);
        }

        // Write pairs (hi/lo planes) into the other buffer: 4 ds_write_b32.
        unsigned short* Hw = Hs + (((t & 1) ^ 1) << 11);
#pragma unroll
        for (int p = 0; p < 2; ++p) {
            unsigned hw, lw;
            packpair(hv[2 * p], hv[2 * p + 1], hw, lw);
            *(unsigned*)(Hw + woff[p])        = hw;   // hi plane
            *(unsigned*)(Hw + 1024 + woff[p]) = lw;   // lo plane
        }
        __syncthreads();

        xA0 = xA1; xB0 = xB1; xA1 = xA2; xB1 = xB2;
    }

    // ---- Head: out[b] = sum_u wfc[u] * G[u][b] + b_fc ----
    float s = hv[0] * wfcv[0] + hv[1] * wfcv[1] + hv[2] * wfcv[2] + hv[3] * wfcv[3];
    s += __shfl_xor(s, 16, 64);
    s += __shfl_xor(s, 32, 64);
    if (qd == 0) Ps[nt * 16 + ln] = s;
    __syncthreads();
    if (tid < 16)
        out[b0 + tid] = Ps[tid] + Ps[16 + tid] + Ps[32 + tid] + Ps[48 + tid] + b_fc[0];
}

extern "C" void kernel_launch(void* const* d_in, const int* in_sizes, int n_in,
                              void* d_out, int out_size, void* d_ws, size_t ws_size,
                              hipStream_t stream) {
    const float* x    = (const float*)d_in[0];
    const float* W_ih = (const float*)d_in[1];
    const float* W_hh = (const float*)d_in[2];
    const float* b_ih = (const float*)d_in[3];
    const float* b_hh = (const float*)d_in[4];
    const float* W_fc = (const float*)d_in[5];
    const float* b_fc = (const float*)d_in[6];
    float* out = (float*)d_out;

    // 256 tiles of 16 chains; 4 waves/block (one per SIMD), 1 block per CU.
    rnn_tg_kernel<<<dim3(BATCH / 16), dim3(256), 0, stream>>>(
        x, W_ih, W_hh, b_ih, b_hh, W_fc, b_fc, out);
}

// Round 8
// 343.051 us; speedup vs baseline: 1.7773x; 1.0953x over previous
//
#include <hip/hip_runtime.h>

#define INPUT 32
#define HIDDEN 64
#define BATCH 4096
#define SEQ 256

typedef __attribute__((ext_vector_type(8))) short bf16x8;   // 8 bf16 (4 VGPRs)
typedef __attribute__((ext_vector_type(4))) float floatx4;  // 4 fp32

#define MFMA(a, b, c) __builtin_amdgcn_mfma_f32_16x16x32_bf16((a), (b), (c), 0, 0, 0)

// Custom barrier: wait LDS-only, leave global loads in flight.
// __syncthreads() lowers to s_waitcnt vmcnt(0) lgkmcnt(0) + s_barrier, which
// drained our per-step x prefetch and put ~HBM latency on EVERY step's
// critical path (round-7: 2203 cyc/step with both pipes ~80% idle).
#define LDS_BARRIER() asm volatile("s_waitcnt lgkmcnt(0)\n\ts_barrier" ::: "memory")

// RNE f32->bf16 (setup-only, for static weights).
__device__ __forceinline__ unsigned short f2bf(float f) {
    unsigned u = __float_as_uint(f);
    u += 0x7fffu + ((u >> 16) & 1u);
    return (unsigned short)(u >> 16);
}
__device__ __forceinline__ float bf2f(unsigned short b) {
    return __uint_as_float(((unsigned)b) << 16);
}
__device__ __forceinline__ void split8(const float f[8], bf16x8& hi, bf16x8& lo) {
#pragma unroll
    for (int j = 0; j < 8; ++j) {
        unsigned short h = f2bf(f[j]);
        hi[j] = (short)h;
        lo[j] = (short)f2bf(f[j] - bf2f(h));
    }
}

// Truncation split of a pair -> packed hi/lo words (6 VALU).
__device__ __forceinline__ void packpair(float f0, float f1, unsigned& hw, unsigned& lw) {
    unsigned b0 = __float_as_uint(f0), b1 = __float_as_uint(f1);
    float h0 = __uint_as_float(b0 & 0xffff0000u);
    float h1 = __uint_as_float(b1 & 0xffff0000u);
    float l0 = f0 - h0, l1 = f1 - h1;
    hw = __builtin_amdgcn_perm(b1, b0, 0x07060302u);
    lw = __builtin_amdgcn_perm(__float_as_uint(l1), __float_as_uint(l0), 0x07060302u);
}

union FragU { bf16x8 v; unsigned u[4]; };

// Transposed-state N-split MFMA RNN (round-7 structure) + two chain cuts:
//  (a) raw LDS-only barrier (no vmcnt drain -> prefetch survives the barrier)
//  (b) ih-projection for step t+1 computed during step t (G-independent),
//      seeding the hh accumulator -> G-dependent MFMA chain depth 3, not 6.
// Layouts (verified r5-r7): C/D row=4qd+reg (hidden u), col=ln (batch).
//   A: m=ln (W row), k=8qd+j.  B: n=ln (batch), k=8qd+j (+32kt).
// G in LDS (u16): buf*2048 + pl*1024 + kt*512 + ln*32 + slot*8 + j,
//   slot=(qd+(ln>>1))&3 -> reads/writes <=2-way per phase (2-way free, m136).
__global__ __launch_bounds__(256, 1) void rnn_tg2_kernel(
    const float* __restrict__ x,     // [B, T, 32]
    const float* __restrict__ W_ih,  // [64, 32]
    const float* __restrict__ W_hh,  // [64, 64]
    const float* __restrict__ b_ih,  // [64]
    const float* __restrict__ b_hh,  // [64]
    const float* __restrict__ W_fc,  // [1, 64]
    const float* __restrict__ b_fc,  // [1]
    float* __restrict__ out)         // [B, 1]
{
    const int tid  = threadIdx.x;
    const int nt   = tid >> 6;        // wave id: owns hidden rows [16nt, 16nt+16)
    const int lane = tid & 63;
    const int ln   = lane & 15;
    const int qd   = lane >> 4;
    const int b0   = blockIdx.x * 16;

    __shared__ __align__(16) unsigned short Hs[4096];  // 2 buffers of G hi/lo
    __shared__ float Ps[64];

    { // zero buffer 0 (h_{-1} = 0)
        unsigned* z = (unsigned*)Hs;
        for (int i = tid; i < 1024; i += 256) z[i] = 0u;
    }

    // ---- Static A-operand weights (row m = 16nt+ln), RNE hi/lo split ----
    const int mrow = nt * 16 + ln;
    bf16x8 WihH, WihL, WhhH[2], WhhL[2];
    {
        float f[8];
        const float* ri = W_ih + mrow * INPUT + qd * 8;
        *(float4*)&f[0] = *(const float4*)ri;
        *(float4*)&f[4] = *(const float4*)(ri + 4);
        split8(f, WihH, WihL);
        const float* rh = W_hh + mrow * HIDDEN + qd * 8;
#pragma unroll
        for (int kt = 0; kt < 2; ++kt) {
            *(float4*)&f[0] = *(const float4*)(rh + kt * 32);
            *(float4*)&f[4] = *(const float4*)(rh + kt * 32 + 4);
            split8(f, WhhH[kt], WhhL[kt]);
        }
    }
    const int u0 = nt * 16 + qd * 4;   // this lane's 4 output rows
    floatx4 bbv, wfcv;
    {
        float4 bi = *(const float4*)(b_ih + u0);
        float4 bh = *(const float4*)(b_hh + u0);
        bbv[0] = bi.x + bh.x; bbv[1] = bi.y + bh.y;
        bbv[2] = bi.z + bh.z; bbv[3] = bi.w + bh.w;
        float4 wf = *(const float4*)(W_fc + u0);
        wfcv[0] = wf.x; wfcv[1] = wf.y; wfcv[2] = wf.z; wfcv[3] = wf.w;
    }

    const int rbase = ln * 32 + ((qd + (ln >> 1)) & 3) * 8;
    int woff[2];
#pragma unroll
    for (int p = 0; p < 2; ++p) {
        const int up = u0 + 2 * p;
        woff[p] = (up >> 5) * 512 + ln * 32 + ((((up >> 3) & 3) + (ln >> 1)) & 3) * 8 + (up & 7);
    }

    const float* xp = x + (size_t)(b0 + ln) * (SEQ * INPUT) + qd * 8;

    // 2-deep x prefetch (now actually survives the barrier).
    float4 xA0 = *(const float4*)(xp);
    float4 xB0 = *(const float4*)(xp + 4);
    float4 xA1 = *(const float4*)(xp + INPUT);
    float4 xB1 = *(const float4*)(xp + INPUT + 4);

    // ih-projection for t=0 (G-independent preamble).
    floatx4 ihacc;
    {
        FragU xH, xL;
        packpair(xA0.x, xA0.y, xH.u[0], xL.u[0]);
        packpair(xA0.z, xA0.w, xH.u[1], xL.u[1]);
        packpair(xB0.x, xB0.y, xH.u[2], xL.u[2]);
        packpair(xB0.z, xB0.w, xH.u[3], xL.u[3]);
        ihacc = bbv;
        ihacc = MFMA(WihH, xH.v, ihacc);
        ihacc = MFMA(WihH, xL.v, ihacc);
        ihacc = MFMA(WihL, xH.v, ihacc);
    }

    __syncthreads();  // once: zero-init + weight loads settled

    float hv[4] = {0.f, 0.f, 0.f, 0.f};

#pragma unroll 1
    for (int t = 0; t < SEQ; ++t) {
        // Prefetch x_{t+2}.
        const int tn = (t + 2 < SEQ) ? t + 2 : SEQ - 1;
        float4 xA2 = *(const float4*)(xp + tn * INPUT);
        float4 xB2 = *(const float4*)(xp + tn * INPUT + 4);

        // G B-frags for step t: 4 ds_read_b128 (<=2-way conflicts).
        const unsigned short* Hr = Hs + ((t & 1) << 11) + rbase;
        bf16x8 gH0 = *(const bf16x8*)(Hr);          // pl0 kt0
        bf16x8 gH1 = *(const bf16x8*)(Hr + 512);    // pl0 kt1
        bf16x8 gL0 = *(const bf16x8*)(Hr + 1024);   // pl1 kt0
        bf16x8 gL1 = *(const bf16x8*)(Hr + 1536);   // pl1 kt1

        // Off-path: ih-projection for t+1 (fills the ds_read wait).
        FragU nxH, nxL;
        packpair(xA1.x, xA1.y, nxH.u[0], nxL.u[0]);
        packpair(xA1.z, xA1.w, nxH.u[1], nxL.u[1]);
        packpair(xB1.x, xB1.y, nxH.u[2], nxL.u[2]);
        packpair(xB1.z, xB1.w, nxH.u[3], nxL.u[3]);
        floatx4 ihn = bbv;
        ihn = MFMA(WihH, nxH.v, ihn);
        ihn = MFMA(WihH, nxL.v, ihn);
        ihn = MFMA(WihL, nxH.v, ihn);

        // G-dependent chains: depth 3 each.
        floatx4 a = ihacc;
        a = MFMA(WhhH[0], gH0, a);
        a = MFMA(WhhH[0], gL0, a);
        a = MFMA(WhhL[0], gH0, a);
        floatx4 a2 = {0.f, 0.f, 0.f, 0.f};
        a2 = MFMA(WhhH[1], gH1, a2);
        a2 = MFMA(WhhH[1], gL1, a2);
        a2 = MFMA(WhhL[1], gH1, a2);

        // tanh -> new G rows u0..u0+3 (batch col ln).
#pragma unroll
        for (int r = 0; r < 4; ++r) {
            float p = a[r] + a2[r];
            float e = __expf(2.0f * p);
            hv[r] = 1.0f - 2.0f * __builtin_amdgcn_rcpf(e + 1.0f);
        }

        // Writer-side split into the other buffer: 4 ds_write_b32.
        unsigned short* Hw = Hs + (((t & 1) ^ 1) << 11);
#pragma unroll
        for (int p = 0; p < 2; ++p) {
            unsigned hw, lw;
            packpair(hv[2 * p], hv[2 * p + 1], hw, lw);
            *(unsigned*)(Hw + woff[p])        = hw;   // hi plane
            *(unsigned*)(Hw + 1024 + woff[p]) = lw;   // lo plane
        }

        LDS_BARRIER();   // LDS-only drain; x loads stay in flight.

        ihacc = ihn;
        xA0 = xA1; xB0 = xB1; xA1 = xA2; xB1 = xB2;
    }

    // ---- Head: out[b] = sum_u wfc[u] * G[u][b] + b_fc ----
    float s = hv[0] * wfcv[0] + hv[1] * wfcv[1] + hv[2] * wfcv[2] + hv[3] * wfcv[3];
    s += __shfl_xor(s, 16, 64);
    s += __shfl_xor(s, 32, 64);
    if (qd == 0) Ps[nt * 16 + ln] = s;
    __syncthreads();
    if (tid < 16)
        out[b0 + tid] = Ps[tid] + Ps[16 + tid] + Ps[32 + tid] + Ps[48 + tid] + b_fc[0];
}

extern "C" void kernel_launch(void* const* d_in, const int* in_sizes, int n_in,
                              void* d_out, int out_size, void* d_ws, size_t ws_size,
                              hipStream_t stream) {
    const float* x    = (const float*)d_in[0];
    const float* W_ih = (const float*)d_in[1];
    const float* W_hh = (const float*)d_in[2];
    const float* b_ih = (const float*)d_in[3];
    const float* b_hh = (const float*)d_in[4];
    const float* W_fc = (const float*)d_in[5];
    const float* b_fc = (const float*)d_in[6];
    float* out = (float*)d_out;

    // 256 tiles of 16 chains; 4 waves/block (one per SIMD), 1 block per CU.
    rnn_tg2_kernel<<<dim3(BATCH / 16), dim3(256), 0, stream>>>(
        x, W_ih, W_hh, b_ih, b_hh, W_fc, b_fc, out);
}

// Round 9
// 303.258 us; speedup vs baseline: 2.0105x; 1.1312x over previous
//
#include <hip/hip_runtime.h>

#define INPUT 32
#define HIDDEN 64
#define BATCH 4096
#define SEQ 256

typedef __attribute__((ext_vector_type(8))) short bf16x8;   // 8 bf16 (4 VGPRs)
typedef __attribute__((ext_vector_type(4))) float floatx4;  // 4 fp32

#define MFMA(a, b, c) __builtin_amdgcn_mfma_f32_16x16x32_bf16((a), (b), (c), 0, 0, 0)

// LDS-only barrier: wait LDS ops, leave global loads in flight
// (__syncthreads drains vmcnt(0) -> would kill the x prefetch pipeline).
#define LDS_BARRIER() asm volatile("s_waitcnt lgkmcnt(0)\n\ts_barrier" ::: "memory")

// RNE f32->bf16 (setup-only, for static weights).
__device__ __forceinline__ unsigned short f2bf(float f) {
    unsigned u = __float_as_uint(f);
    u += 0x7fffu + ((u >> 16) & 1u);
    return (unsigned short)(u >> 16);
}
__device__ __forceinline__ float bf2f(unsigned short b) {
    return __uint_as_float(((unsigned)b) << 16);
}
__device__ __forceinline__ void split8(const float f[8], bf16x8& hi, bf16x8& lo) {
#pragma unroll
    for (int j = 0; j < 8; ++j) {
        unsigned short h = f2bf(f[j]);
        hi[j] = (short)h;
        lo[j] = (short)f2bf(f[j] - bf2f(h));
    }
}

// Truncation split of a pair -> packed hi/lo words (6 VALU).
__device__ __forceinline__ void packpair(float f0, float f1, unsigned& hw, unsigned& lw) {
    unsigned b0 = __float_as_uint(f0), b1 = __float_as_uint(f1);
    float h0 = __uint_as_float(b0 & 0xffff0000u);
    float h1 = __uint_as_float(b1 & 0xffff0000u);
    float l0 = f0 - h0, l1 = f1 - h1;
    hw = __builtin_amdgcn_perm(b1, b0, 0x07060302u);
    lw = __builtin_amdgcn_perm(__float_as_uint(l1), __float_as_uint(l0), 0x07060302u);
}

union FragU { bf16x8 v; unsigned u[4]; };

// Round-8 diagnosis: ~1300 idle cyc/step; the only 900-cyc-scale latency is
// the x load, and the 2-deep prefetch gave the used value only 1 step of
// slack -> per-step vmcnt wait ~400-900 cyc, maxed across 4 waves by the
// barrier. Fix: 4-slot circular x buffer + unroll-4 (compile-time slots, no
// shift movs). Used x is loaded 3 steps (~2000+ cyc) ahead -> wait ~0.
// Everything else identical to round 8 (isolate one variable).
__global__ __launch_bounds__(256, 1) void rnn_tg3_kernel(
    const float* __restrict__ x,     // [B, T, 32]
    const float* __restrict__ W_ih,  // [64, 32]
    const float* __restrict__ W_hh,  // [64, 64]
    const float* __restrict__ b_ih,  // [64]
    const float* __restrict__ b_hh,  // [64]
    const float* __restrict__ W_fc,  // [1, 64]
    const float* __restrict__ b_fc,  // [1]
    float* __restrict__ out)         // [B, 1]
{
    const int tid  = threadIdx.x;
    const int nt   = tid >> 6;        // wave id: owns hidden rows [16nt, 16nt+16)
    const int lane = tid & 63;
    const int ln   = lane & 15;
    const int qd   = lane >> 4;
    const int b0   = blockIdx.x * 16;

    __shared__ __align__(16) unsigned short Hs[4096];  // 2 buffers of G hi/lo
    __shared__ float Ps[64];

    { // zero buffer 0 (h_{-1} = 0)
        unsigned* z = (unsigned*)Hs;
        for (int i = tid; i < 1024; i += 256) z[i] = 0u;
    }

    // ---- Static A-operand weights (row m = 16nt+ln), RNE hi/lo split ----
    const int mrow = nt * 16 + ln;
    bf16x8 WihH, WihL, WhhH[2], WhhL[2];
    {
        float f[8];
        const float* ri = W_ih + mrow * INPUT + qd * 8;
        *(float4*)&f[0] = *(const float4*)ri;
        *(float4*)&f[4] = *(const float4*)(ri + 4);
        split8(f, WihH, WihL);
        const float* rh = W_hh + mrow * HIDDEN + qd * 8;
#pragma unroll
        for (int kt = 0; kt < 2; ++kt) {
            *(float4*)&f[0] = *(const float4*)(rh + kt * 32);
            *(float4*)&f[4] = *(const float4*)(rh + kt * 32 + 4);
            split8(f, WhhH[kt], WhhL[kt]);
        }
    }
    const int u0 = nt * 16 + qd * 4;   // this lane's 4 output rows
    floatx4 bbv, wfcv;
    {
        float4 bi = *(const float4*)(b_ih + u0);
        float4 bh = *(const float4*)(b_hh + u0);
        bbv[0] = bi.x + bh.x; bbv[1] = bi.y + bh.y;
        bbv[2] = bi.z + bh.z; bbv[3] = bi.w + bh.w;
        float4 wf = *(const float4*)(W_fc + u0);
        wfcv[0] = wf.x; wfcv[1] = wf.y; wfcv[2] = wf.z; wfcv[3] = wf.w;
    }

    const int rbase = ln * 32 + ((qd + (ln >> 1)) & 3) * 8;
    int woff[2];
#pragma unroll
    for (int p = 0; p < 2; ++p) {
        const int up = u0 + 2 * p;
        woff[p] = (up >> 5) * 512 + ln * 32 + ((((up >> 3) & 3) + (ln >> 1)) & 3) * 8 + (up & 7);
    }

    const float* xp = x + (size_t)(b0 + ln) * (SEQ * INPUT) + qd * 8;

    // 4-slot circular x prefetch: slot s holds x[t] with t === s (mod 4).
    float4 xa[4], xb[4];
#pragma unroll
    for (int i = 0; i < 4; ++i) {
        xa[i] = *(const float4*)(xp + i * INPUT);
        xb[i] = *(const float4*)(xp + i * INPUT + 4);
    }

    // ih-projection for t=0 (slot 0), off the recurrent path.
    floatx4 ihacc;
    {
        FragU xH, xL;
        packpair(xa[0].x, xa[0].y, xH.u[0], xL.u[0]);
        packpair(xa[0].z, xa[0].w, xH.u[1], xL.u[1]);
        packpair(xb[0].x, xb[0].y, xH.u[2], xL.u[2]);
        packpair(xb[0].z, xb[0].w, xH.u[3], xL.u[3]);
        ihacc = bbv;
        ihacc = MFMA(WihH, xH.v, ihacc);
        ihacc = MFMA(WihH, xL.v, ihacc);
        ihacc = MFMA(WihL, xH.v, ihacc);
    }

    __syncthreads();  // once: zero-init settled

    float hv[4] = {0.f, 0.f, 0.f, 0.f};

#pragma unroll 1
    for (int tb = 0; tb < SEQ; tb += 4) {
#pragma unroll
        for (int s = 0; s < 4; ++s) {
            const int t = tb + s;
            // Refill slot s with x[t+4] (clamped dup at tail; harmless).
            const int tn = (t + 4 < SEQ) ? t + 4 : SEQ - 1;
            xa[s] = *(const float4*)(xp + tn * INPUT);
            xb[s] = *(const float4*)(xp + tn * INPUT + 4);

            // G B-frags for step t: 4 ds_read_b128 (<=2-way conflicts).
            const unsigned short* Hr = Hs + ((t & 1) << 11) + rbase;
            bf16x8 gH0 = *(const bf16x8*)(Hr);          // pl0 kt0
            bf16x8 gH1 = *(const bf16x8*)(Hr + 512);    // pl0 kt1
            bf16x8 gL0 = *(const bf16x8*)(Hr + 1024);   // pl1 kt0
            bf16x8 gL1 = *(const bf16x8*)(Hr + 1536);   // pl1 kt1

            // Off-path: ih-projection for t+1 from slot (s+1)&3
            // (that x was loaded 3 steps ago -> vmcnt wait ~0).
            const float4 na = xa[(s + 1) & 3], nb = xb[(s + 1) & 3];
            FragU nxH, nxL;
            packpair(na.x, na.y, nxH.u[0], nxL.u[0]);
            packpair(na.z, na.w, nxH.u[1], nxL.u[1]);
            packpair(nb.x, nb.y, nxH.u[2], nxL.u[2]);
            packpair(nb.z, nb.w, nxH.u[3], nxL.u[3]);
            floatx4 ihn = bbv;
            ihn = MFMA(WihH, nxH.v, ihn);
            ihn = MFMA(WihH, nxL.v, ihn);
            ihn = MFMA(WihL, nxH.v, ihn);

            // G-dependent chains: depth 3 each.
            floatx4 a = ihacc;
            a = MFMA(WhhH[0], gH0, a);
            a = MFMA(WhhH[0], gL0, a);
            a = MFMA(WhhL[0], gH0, a);
            floatx4 a2 = {0.f, 0.f, 0.f, 0.f};
            a2 = MFMA(WhhH[1], gH1, a2);
            a2 = MFMA(WhhH[1], gL1, a2);
            a2 = MFMA(WhhL[1], gH1, a2);

            // tanh -> new G rows u0..u0+3 (batch col ln).
#pragma unroll
            for (int r = 0; r < 4; ++r) {
                float p = a[r] + a2[r];
                float e = __expf(2.0f * p);
                hv[r] = 1.0f - 2.0f * __builtin_amdgcn_rcpf(e + 1.0f);
            }

            // Writer-side split into the other buffer: 4 ds_write_b32.
            unsigned short* Hw = Hs + (((t & 1) ^ 1) << 11);
#pragma unroll
            for (int p = 0; p < 2; ++p) {
                unsigned hw, lw;
                packpair(hv[2 * p], hv[2 * p + 1], hw, lw);
                *(unsigned*)(Hw + woff[p])        = hw;   // hi plane
                *(unsigned*)(Hw + 1024 + woff[p]) = lw;   // lo plane
            }

            LDS_BARRIER();   // LDS-only drain; x loads stay in flight.
            ihacc = ihn;
        }
    }

    // ---- Head: out[b] = sum_u wfc[u] * G[u][b] + b_fc ----
    float s = hv[0] * wfcv[0] + hv[1] * wfcv[1] + hv[2] * wfcv[2] + hv[3] * wfcv[3];
    s += __shfl_xor(s, 16, 64);
    s += __shfl_xor(s, 32, 64);
    if (qd == 0) Ps[nt * 16 + ln] = s;
    __syncthreads();
    if (tid < 16)
        out[b0 + tid] = Ps[tid] + Ps[16 + tid] + Ps[32 + tid] + Ps[48 + tid] + b_fc[0];
}

extern "C" void kernel_launch(void* const* d_in, const int* in_sizes, int n_in,
                              void* d_out, int out_size, void* d_ws, size_t ws_size,
                              hipStream_t stream) {
    const float* x    = (const float*)d_in[0];
    const float* W_ih = (const float*)d_in[1];
    const float* W_hh = (const float*)d_in[2];
    const float* b_ih = (const float*)d_in[3];
    const float* b_hh = (const float*)d_in[4];
    const float* W_fc = (const float*)d_in[5];
    const float* b_fc = (const float*)d_in[6];
    float* out = (float*)d_out;

    // 256 tiles of 16 chains; 4 waves/block (one per SIMD), 1 block per CU.
    rnn_tg3_kernel<<<dim3(BATCH / 16), dim3(256), 0, stream>>>(
        x, W_ih, W_hh, b_ih, b_hh, W_fc, b_fc, out);
}